// Round 5
// baseline (349.268 us; speedup 1.0000x reference)
//
#include <hip/hip_runtime.h>
#include <stdint.h>
#include <math.h>

#define BLOCK 64          // ONE wave per block
#define SEL0 46
#define SEL1 92
#define ASEL0 16
#define ASEL1 32
#define NNB 138           // SEL0+SEL1
#define NANG 48           // ASEL0+ASEL1
#define DDIM 282          // NNB + 3*NANG
#define HID 64
#define FEPS 1e-16f
#define CAP 128           // per-type candidate cap (wave-sortable)
#define NREP 16           // force-scatter replicas
#define QMAX 16           // packed key pairs per lane (2 atoms each -> N<=2048)
#define W0T_ALLOC (DDIM*HID + 64)   // padded for unconditional 5th-acc read

__device__ __forceinline__ float mimg(float dx, float box, float ibox) {
    return dx - box * rintf(dx * ibox);   // jnp.round = rintf
}

// sum NREP replicas -> out.  out = [energy(B) | forces(3BN)]
__global__ __launch_bounds__(256)
void reduce_kernel(const float* __restrict__ rep, float* __restrict__ out,
                   int total, int Bc, int eoff, int rstride, int nrep)
{
    int e = blockIdx.x * 256 + threadIdx.x;
    if (e >= total) return;
    int src = (e < Bc) ? (eoff + e) : (e - Bc);
    float s = 0.0f;
    for (int r = 0; r < nrep; ++r) s += rep[(size_t)r * rstride + src];
    out[e] = s;
}

// W0T[m*DDIM+d] = W0[d*HID+m];  W1T[m*HID+l] = W1[l*HID+m]
__global__ __launch_bounds__(256)
void tr_kernel(const float* __restrict__ W0a, const float* __restrict__ W0b,
               const float* __restrict__ W1a, const float* __restrict__ W1b,
               float* __restrict__ W0Ta, float* __restrict__ W0Tb,
               float* __restrict__ W1Ta, float* __restrict__ W1Tb)
{
    int idx = blockIdx.x * 256 + threadIdx.x;
    if (idx < DDIM * HID) {
        int d = idx / HID, m = idx % HID;
        W0Ta[m * DDIM + d] = W0a[idx];
        W0Tb[m * DDIM + d] = W0b[idx];
    }
    if (idx < HID * HID) {
        int l = idx / HID, m = idx % HID;
        W1Ta[m * HID + l] = W1a[idx];
        W1Tb[m * HID + l] = W1b[idx];
    }
}

__global__ __launch_bounds__(BLOCK)
void md_kernel(const float* __restrict__ xyz, const int* __restrict__ types,
               const void* __restrict__ boxp,
               const float* __restrict__ W0a, const float* __restrict__ B0a,
               const float* __restrict__ W1a, const float* __restrict__ B1a,
               const float* __restrict__ W2a, const float* __restrict__ B2a,
               const float* __restrict__ W0b, const float* __restrict__ B0b,
               const float* __restrict__ W1b, const float* __restrict__ B1b,
               const float* __restrict__ W2b, const float* __restrict__ B2b,
               const float* __restrict__ W0Ta, const float* __restrict__ W0Tb,
               const float* __restrict__ W1Ta, const float* __restrict__ W1Tb,
               float* __restrict__ out, float* __restrict__ repbase,
               int nrep, int eoff, int rstride, int B, int N)
{
    const int atom = blockIdx.x;
    const int b = atom / N;
    const int i = atom - b * N;
    const int lane = threadIdx.x;

    __shared__ unsigned long long A0[CAP], A1[CAP];
    __shared__ float snd[NNB];
    __shared__ int   sni[NNB];
    __shared__ float sdesc[DDIM];
    __shared__ float sg[DDIM];
    __shared__ float sA[9];
    __shared__ float sh1[HID], sdh2[HID], sdh1[HID];
    __shared__ float sG[9];
    __shared__ float sFi[3];
    __shared__ int sCnt0, sCnt1;

    // replica targets
    float* Fout; float* Eout;
    if (repbase) {
        float* base = repbase + (size_t)(blockIdx.x % nrep) * rstride;
        Fout = base; Eout = base + eoff;
    } else {
        Fout = out + B; Eout = out;
    }

    int ib_test = ((const int*)boxp)[0];
    float box = (ib_test > 0 && ib_test < 1000000) ? (float)ib_test
                                                   : ((const float*)boxp)[0];
    float ibox = 1.0f / box;

    const float* X = xyz + (size_t)b * N * 3;
    const int*   T = types + (size_t)b * N;
    const int ti = T[i];
    const float xi = X[3*i+0], yi = X[3*i+1], zi = X[3*i+2];

    // ---- 16-bit keys, 2 per u32 register: k16 = type<<15 | fpbits(d)[30:16] ----
    uint32_t kp[QMAX];
    uint32_t t1cnt = 0;
    #pragma unroll
    for (int q = 0; q < QMAX; ++q) {
        uint32_t kA = 0xFFFFu, kB = 0xFFFFu;
        int j0 = (2*q) * BLOCK + lane;
        int j1 = (2*q+1) * BLOCK + lane;
        if (j0 < N && j0 != i) {
            float dx = mimg(xi - X[3*j0+0], box, ibox);
            float dy = mimg(yi - X[3*j0+1], box, ibox);
            float dz = mimg(zi - X[3*j0+2], box, ibox);
            float d = sqrtf(dx*dx + dy*dy + dz*dz);
            kA = (__float_as_uint(d) >> 16) | (T[j0] ? 0x8000u : 0u);
        }
        if (j1 < N && j1 != i) {
            float dx = mimg(xi - X[3*j1+0], box, ibox);
            float dy = mimg(yi - X[3*j1+1], box, ibox);
            float dz = mimg(zi - X[3*j1+2], box, ibox);
            float d = sqrtf(dx*dx + dy*dy + dz*dz);
            kB = (__float_as_uint(d) >> 16) | (T[j1] ? 0x8000u : 0u);
        }
        kp[q] = kA | (kB << 16);
        t1cnt += (kA >> 15) + (kB >> 15);
    }
    // wave butterfly: all lanes get totals. invalid entries (self/pad) have type bit set.
    #pragma unroll
    for (int o = 1; o < 64; o <<= 1) t1cnt += __shfl_xor(t1cnt, o, 64);
    const int n_invalid = (QMAX*2*BLOCK - N) + 1;   // pads + self
    const int tot1 = (int)t1cnt - n_invalid;
    const int tot0 = (N - 1) - tot1;
    const int need0 = min(SEL0, tot0);
    const int need1 = min(SEL1, tot1);

    // ---- integer bisection on 15-bit key space (no LDS, no barriers) ----
    const float vol = box * box * box;
    const float c43pi = 4.18879020f;
    float R0 = cbrtf(0.5f * (need0 + CAP) * vol / (c43pi * fmaxf((float)tot0, 1.0f)));
    float R1 = cbrtf(0.5f * (need1 + CAP) * vol / (c43pi * fmaxf((float)tot1, 1.0f)));
    uint32_t thr0 = (__float_as_uint(R0) >> 16) & 0x7FFFu;
    uint32_t thr1 = (__float_as_uint(R1) >> 16) & 0x7FFFu;
    uint32_t lo0 = 0, hi0 = 0x7FFFu, lo1 = 0, hi1 = 0x7FFFu;
    for (int it = 0; it < 18; ++it) {
        uint32_t c0 = 0, c1 = 0;
        #pragma unroll
        for (int q = 0; q < QMAX; ++q) {
            uint32_t ka = kp[q] & 0xFFFFu, kb = kp[q] >> 16;
            c0 += (ka < 0x8000u && ka < thr0);
            c0 += (kb < 0x8000u && kb < thr0);
            c1 += (ka >= 0x8000u && (ka & 0x7FFFu) < thr1);
            c1 += (kb >= 0x8000u && (kb & 0x7FFFu) < thr1);
        }
        uint32_t packed = c0 | (c1 << 16);
        #pragma unroll
        for (int o = 1; o < 64; o <<= 1) packed += __shfl_xor(packed, o, 64);
        int cc0 = (int)(packed & 0xFFFFu), cc1 = (int)(packed >> 16);
        bool d0 = (cc0 >= need0 && cc0 <= CAP);
        bool d1 = (cc1 >= need1 && cc1 <= CAP);
        if (d0 && d1) break;
        if (!d0) { if (cc0 < need0) lo0 = thr0; else hi0 = thr0; thr0 = (lo0 + hi0) >> 1; }
        if (!d1) { if (cc1 < need1) lo1 = thr1; else hi1 = thr1; thr1 = (lo1 + hi1) >> 1; }
    }

    // ---- compact candidates (recompute exact distance for hits) ----
    if (lane == 0) { sCnt0 = 0; sCnt1 = 0; }
    __syncthreads();
    #pragma unroll
    for (int q = 0; q < QMAX; ++q) {
        #pragma unroll
        for (int h = 0; h < 2; ++h) {
            uint32_t k = (h == 0) ? (kp[q] & 0xFFFFu) : (kp[q] >> 16);
            bool is1 = (k >= 0x8000u);
            uint32_t kd = k & 0x7FFFu;
            bool hit = is1 ? (kd < thr1) : (kd < thr0);
            if (hit) {
                int j = (2*q + h) * BLOCK + lane;
                float dx = mimg(xi - X[3*j+0], box, ibox);
                float dy = mimg(yi - X[3*j+1], box, ibox);
                float dz = mimg(zi - X[3*j+2], box, ibox);
                float d = sqrtf(dx*dx + dy*dy + dz*dz);
                unsigned long long key =
                    ((unsigned long long)__float_as_uint(d) << 32) | (uint32_t)j;
                if (is1) { int pos = atomicAdd(&sCnt1, 1); if (pos < CAP) A1[pos] = key; }
                else     { int pos = atomicAdd(&sCnt0, 1); if (pos < CAP) A0[pos] = key; }
            }
        }
    }
    __syncthreads();
    const int c0 = min(sCnt0, CAP);
    const int c1 = min(sCnt1, CAP);
    if (lane      >= c0) A0[lane]      = ~0ull;
    if (lane + 64 >= c0) A0[lane + 64] = ~0ull;
    if (lane      >= c1) A1[lane]      = ~0ull;
    if (lane + 64 >= c1) A1[lane + 64] = ~0ull;
    __syncthreads();

    // ---- dual interleaved register bitonic sort (both arrays, one wave) ----
    {
        unsigned long long a0 = A0[lane], a1 = A0[lane + 64];
        unsigned long long b0 = A1[lane], b1 = A1[lane + 64];
        #pragma unroll
        for (int size = 2; size <= 128; size <<= 1) {
            #pragma unroll
            for (int stride = 64; stride > 0; stride >>= 1) {
                if (stride >= size) continue;
                if (stride == 64) {
                    unsigned long long mn = a0 < a1 ? a0 : a1;
                    unsigned long long mx = a0 < a1 ? a1 : a0;
                    a0 = mn; a1 = mx;
                    mn = b0 < b1 ? b0 : b1;
                    mx = b0 < b1 ? b1 : b0;
                    b0 = mn; b1 = mx;
                } else {
                    bool keep_lo = (lane & stride) == 0;
                    bool asc0 = ((lane & size) == 0);
                    bool asc1 = (((lane + 64) & size) == 0);
                    unsigned long long oa0 = __shfl_xor(a0, stride, 64);
                    unsigned long long oa1 = __shfl_xor(a1, stride, 64);
                    unsigned long long ob0 = __shfl_xor(b0, stride, 64);
                    unsigned long long ob1 = __shfl_xor(b1, stride, 64);
                    a0 = (asc0 == keep_lo) ? (a0 < oa0 ? a0 : oa0) : (a0 > oa0 ? a0 : oa0);
                    a1 = (asc1 == keep_lo) ? (a1 < oa1 ? a1 : oa1) : (a1 > oa1 ? a1 : oa1);
                    b0 = (asc0 == keep_lo) ? (b0 < ob0 ? b0 : ob0) : (b0 > ob0 ? b0 : ob0);
                    b1 = (asc1 == keep_lo) ? (b1 < ob1 ? b1 : ob1) : (b1 > ob1 ? b1 : ob1);
                }
            }
        }
        A0[lane] = a0; A0[lane + 64] = a1;
        A1[lane] = b0; A1[lane + 64] = b1;
    }
    if (lane < 9) sG[lane] = 0.0f;
    if (lane < 3) sFi[lane] = 0.0f;
    __syncthreads();

    // ---- neighbor tables + radial features ----
    for (int s = lane; s < NNB; s += BLOCK) {
        unsigned long long k; bool valid;
        if (s < SEL0) { valid = (s < c0); k = A0[s]; }
        else          { int t2 = s - SEL0; valid = (t2 < c1); k = A1[t2]; }
        float d = 1e30f; int j = -1;
        if (valid) {
            d = __uint_as_float((uint32_t)(k >> 32));
            j = (int)(uint32_t)(k & 0xFFFFFFFFull);
        }
        snd[s] = d; sni[s] = j;
        sdesc[s] = 1.0f / (d + FEPS);
    }
    __syncthreads();

    // ---- local frame (lane 0; state stays in registers) ----
    float f_ld0=1.0f, f_ld1=1.0f; int f_j0=-1, f_j1=-1;
    float r0x=0,r0y=0,r0z=0, r1x=0,r1y=0,r1z=0;
    float u0x=0,u0y=0,u0z=0, u1x=0,u1y=0,u1z=0;
    float f_s=0, f_n2=1, f_n3=1;
    float e2x=0,e2y=0,e2z=0, e3x=0,e3y=0,e3z=0;
    if (lane == 0) {
        float da0 = snd[0],    db0 = snd[SEL0];
        float da1 = snd[1],    db1 = snd[SEL0+1];
        int   ja0 = sni[0],    jb0 = sni[SEL0];
        int   ja1 = sni[1],    jb1 = sni[SEL0+1];
        f_ld0 = (db0 < da0) ? db0 : da0;  f_j0 = (db0 < da0) ? jb0 : ja0;
        f_ld1 = (db1 < da1) ? db1 : da1;  f_j1 = (db1 < da1) ? jb1 : ja1;
        if (f_j0 < 0) f_j0 = i;
        if (f_j1 < 0) f_j1 = i;
        u0x = mimg(xi - X[3*f_j0+0], box, ibox);
        u0y = mimg(yi - X[3*f_j0+1], box, ibox);
        u0z = mimg(zi - X[3*f_j0+2], box, ibox);
        u1x = mimg(xi - X[3*f_j1+0], box, ibox);
        u1y = mimg(yi - X[3*f_j1+1], box, ibox);
        u1z = mimg(zi - X[3*f_j1+2], box, ibox);
        float id0 = 1.0f/(f_ld0 + FEPS), id1 = 1.0f/(f_ld1 + FEPS);
        r0x = u0x*id0; r0y = u0y*id0; r0z = u0z*id0;
        r1x = u1x*id1; r1y = u1y*id1; r1z = u1z*id1;
        f_s = r0x*r1x + r0y*r1y + r0z*r1z;
        float v2x = r1x - f_s*r0x, v2y = r1y - f_s*r0y, v2z = r1z - f_s*r0z;
        f_n2 = sqrtf(v2x*v2x + v2y*v2y + v2z*v2z);
        e2x = v2x/f_n2; e2y = v2y/f_n2; e2z = v2z/f_n2;
        float cx = r0y*r1z - r0z*r1y;
        float cy = r0z*r1x - r0x*r1z;
        float cz = r0x*r1y - r0y*r1x;
        f_n3 = sqrtf(cx*cx + cy*cy + cz*cz);
        e3x = cx/f_n3; e3y = cy/f_n3; e3z = cz/f_n3;
        sA[0]=r0x; sA[1]=r0y; sA[2]=r0z;
        sA[3]=e2x; sA[4]=e2y; sA[5]=e2z;
        sA[6]=e3x; sA[7]=e3y; sA[8]=e3z;
    }
    __syncthreads();

    // ---- angular features ----
    if (lane < NANG) {
        int slot = (lane < ASEL0) ? lane : SEL0 + (lane - ASEL0);
        float d = snd[slot]; int j = sni[slot];
        float dx = 0, dy = 0, dz = 0;
        if (j >= 0) {
            dx = mimg(xi - X[3*j+0], box, ibox);
            dy = mimg(yi - X[3*j+1], box, ibox);
            dz = mimg(zi - X[3*j+2], box, ibox);
        }
        float de = d + FEPS;
        float q = 1.0f/(de*de);
        float wx = sA[0]*dx + sA[1]*dy + sA[2]*dz;
        float wy = sA[3]*dx + sA[4]*dy + sA[5]*dz;
        float wz = sA[6]*dx + sA[7]*dy + sA[8]*dz;
        sdesc[NNB + 3*lane + 0] = wx*q;
        sdesc[NNB + 3*lane + 1] = wy*q;
        sdesc[NNB + 3*lane + 2] = wz*q;
    }
    __syncthreads();

    // ---- MLP forward + backward (one wave; lane == hidden index) ----
    const float* W0 = ti ? W0b : W0a;  const float* B0 = ti ? B0b : B0a;
    const float* W1 = ti ? W1b : W1a;  const float* B1 = ti ? B1b : B1a;
    const float* W2 = ti ? W2b : W2a;  const float* B2 = ti ? B2b : B2a;
    const float* W0T = ti ? W0Tb : W0Ta;
    const float* W1T = ti ? W1Tb : W1Ta;

    float acc0 = B0[lane];
    #pragma unroll 4
    for (int d = 0; d < DDIM; ++d) acc0 = fmaf(sdesc[d], W0[d*HID + lane], acc0);
    float h1 = tanhf(acc0);
    sh1[lane] = h1;
    __syncthreads();

    float acc1 = B1[lane];
    #pragma unroll 8
    for (int m = 0; m < HID; ++m) acc1 = fmaf(sh1[m], W1[m*HID + lane], acc1);
    float h2 = tanhf(acc1);
    float w2 = W2[lane];
    float part = h2 * w2;
    #pragma unroll
    for (int o = 32; o > 0; o >>= 1) part += __shfl_down(part, o, 64);
    if (lane == 0) atomicAdd(&Eout[b], part + B2[0]);
    sdh2[lane] = (1.0f - h2*h2) * w2;
    __syncthreads();

    float acc2 = 0.0f;
    if (W1T) {
        #pragma unroll 8
        for (int m = 0; m < HID; ++m) acc2 = fmaf(W1T[m*HID + lane], sdh2[m], acc2);
    } else {
        for (int m = 0; m < HID; ++m) acc2 = fmaf(W1[lane*HID + m], sdh2[m], acc2);
    }
    sdh1[lane] = (1.0f - h1*h1) * acc2;
    __syncthreads();

    if (W0T) {
        float g0=0, g1=0, g2=0, g3=0, g4=0;
        #pragma unroll 4
        for (int m = 0; m < HID; ++m) {
            float dh = sdh1[m];
            const float* row = W0T + m*DDIM;
            g0 = fmaf(row[lane      ], dh, g0);
            g1 = fmaf(row[lane +  64], dh, g1);
            g2 = fmaf(row[lane + 128], dh, g2);
            g3 = fmaf(row[lane + 192], dh, g3);
            g4 = fmaf(row[lane + 256], dh, g4);   // padded alloc covers OOB
        }
        sg[lane      ] = g0;
        sg[lane +  64] = g1;
        sg[lane + 128] = g2;
        sg[lane + 192] = g3;
        if (lane + 256 < DDIM) sg[lane + 256] = g4;
    } else {
        for (int d = lane; d < DDIM; d += BLOCK) {
            float a = 0.0f;
            for (int m = 0; m < HID; ++m) a = fmaf(W0[d*HID + m], sdh1[m], a);
            sg[d] = a;
        }
    }
    __syncthreads();

    // ---- gradient scatter ----
    for (int s = lane; s < NNB; s += BLOCK) {
        float d = snd[s]; int j = sni[s];
        if (j >= 0) {
            float dx = mimg(xi - X[3*j+0], box, ibox);
            float dy = mimg(yi - X[3*j+1], box, ibox);
            float dz = mimg(zi - X[3*j+2], box, ibox);
            float gr = sg[s];
            float de = d + FEPS;
            float coef = -gr / (d * de * de);
            float gx = coef*dx, gy = coef*dy, gz = coef*dz;
            int a = -1;
            if (s < ASEL0) a = s;
            else if (s >= SEL0 && s < SEL0 + ASEL1) a = ASEL0 + (s - SEL0);
            if (a >= 0) {
                float q = 1.0f/(de*de);
                float gax = sg[NNB+3*a+0], gay = sg[NNB+3*a+1], gaz = sg[NNB+3*a+2];
                float wx = sA[0]*dx + sA[1]*dy + sA[2]*dz;
                float wy = sA[3]*dx + sA[4]*dy + sA[5]*dz;
                float wz = sA[6]*dx + sA[7]*dy + sA[8]*dz;
                float tx = sA[0]*gax + sA[3]*gay + sA[6]*gaz;
                float ty = sA[1]*gax + sA[4]*gay + sA[7]*gaz;
                float tz = sA[2]*gax + sA[5]*gay + sA[8]*gaz;
                float gw = gax*wx + gay*wy + gaz*wz;
                float c2 = -2.0f * gw * q / (de * d);
                gx += q*tx + c2*dx;
                gy += q*ty + c2*dy;
                gz += q*tz + c2*dz;
                atomicAdd(&sG[0], gax*dx*q); atomicAdd(&sG[1], gax*dy*q); atomicAdd(&sG[2], gax*dz*q);
                atomicAdd(&sG[3], gay*dx*q); atomicAdd(&sG[4], gay*dy*q); atomicAdd(&sG[5], gay*dz*q);
                atomicAdd(&sG[6], gaz*dx*q); atomicAdd(&sG[7], gaz*dy*q); atomicAdd(&sG[8], gaz*dz*q);
            }
            float* Fj = Fout + 3*((size_t)b*N + j);
            atomicAdd(&Fj[0], gx); atomicAdd(&Fj[1], gy); atomicAdd(&Fj[2], gz);
            atomicAdd(&sFi[0], -gx); atomicAdd(&sFi[1], -gy); atomicAdd(&sFi[2], -gz);
        }
    }
    __syncthreads();

    // ---- frame backward (lane 0) ----
    if (lane == 0 && f_j0 >= 0) {
        float g0x=sG[0], g0y=sG[1], g0z=sG[2];
        float g2x=sG[3], g2y=sG[4], g2z=sG[5];
        float g3x=sG[6], g3y=sG[7], g3z=sG[8];
        float d3 = g3x*e3x + g3y*e3y + g3z*e3z;
        float in3 = 1.0f/f_n3;
        float dcx = (g3x - d3*e3x)*in3;
        float dcy = (g3y - d3*e3y)*in3;
        float dcz = (g3z - d3*e3z)*in3;
        float gr0x = r1y*dcz - r1z*dcy;
        float gr0y = r1z*dcx - r1x*dcz;
        float gr0z = r1x*dcy - r1y*dcx;
        float gr1x = dcy*r0z - dcz*r0y;
        float gr1y = dcz*r0x - dcx*r0z;
        float gr1z = dcx*r0y - dcy*r0x;
        float d2 = g2x*e2x + g2y*e2y + g2z*e2z;
        float in2 = 1.0f/f_n2;
        float dvx = (g2x - d2*e2x)*in2;
        float dvy = (g2y - d2*e2y)*in2;
        float dvz = (g2z - d2*e2z)*in2;
        gr1x += dvx; gr1y += dvy; gr1z += dvz;
        gr0x -= f_s*dvx; gr0y -= f_s*dvy; gr0z -= f_s*dvz;
        float dss = -(dvx*r0x + dvy*r0y + dvz*r0z);
        gr0x += dss*r1x; gr0y += dss*r1y; gr0z += dss*r1z;
        gr1x += dss*r0x; gr1y += dss*r0y; gr1z += dss*r0z;
        gr0x += g0x; gr0y += g0y; gr0z += g0z;
        float de0 = f_ld0 + FEPS;
        float dot0 = gr0x*u0x + gr0y*u0y + gr0z*u0z;
        float k0 = dot0 / (f_ld0 * de0 * de0);
        float gu0x = gr0x/de0 - k0*u0x;
        float gu0y = gr0y/de0 - k0*u0y;
        float gu0z = gr0z/de0 - k0*u0z;
        float de1 = f_ld1 + FEPS;
        float dot1 = gr1x*u1x + gr1y*u1y + gr1z*u1z;
        float k1 = dot1 / (f_ld1 * de1 * de1);
        float gu1x = gr1x/de1 - k1*u1x;
        float gu1y = gr1y/de1 - k1*u1y;
        float gu1z = gr1z/de1 - k1*u1z;
        float* Fj0 = Fout + 3*((size_t)b*N + f_j0);
        atomicAdd(&Fj0[0], gu0x); atomicAdd(&Fj0[1], gu0y); atomicAdd(&Fj0[2], gu0z);
        float* Fj1 = Fout + 3*((size_t)b*N + f_j1);
        atomicAdd(&Fj1[0], gu1x); atomicAdd(&Fj1[1], gu1y); atomicAdd(&Fj1[2], gu1z);
        sFi[0] -= gu0x + gu1x;
        sFi[1] -= gu0y + gu1y;
        sFi[2] -= gu0z + gu1z;
    }
    __syncthreads();
    if (lane < 3) {
        atomicAdd(&Fout[3*((size_t)b*N + i) + lane], sFi[lane]);
    }
}

extern "C" void kernel_launch(void* const* d_in, const int* in_sizes, int n_in,
                              void* d_out, int out_size, void* d_ws, size_t ws_size,
                              hipStream_t stream) {
    const float* xyz  = (const float*)d_in[0];
    const int*   types = (const int*)d_in[1];
    const void*  boxp = d_in[2];
    int BN = in_sizes[1];              // B*N
    int B = out_size - 3*BN;           // out = energy(B) + forces(3*B*N)
    if (B < 1) B = 1;
    int N = BN / B;

    // ws layout: [replicas nrep*rstride] [W0Ta][W0Tb][W1Ta][W1Tb]
    int eoff = ((3 * BN + 31) / 32) * 32;
    int rstride = eoff + ((B + 31) / 32) * 32;
    int nrep = NREP;
    size_t repBytes = (size_t)nrep * rstride * sizeof(float);
    if (repBytes > ws_size) {
        nrep = (int)(ws_size / ((size_t)rstride * sizeof(float)));
        repBytes = (size_t)nrep * rstride * sizeof(float);
    }
    float* rep = (nrep >= 1) ? (float*)d_ws : nullptr;

    size_t trFloats = 2 * (size_t)W0T_ALLOC + 2 * (size_t)(HID * HID);
    size_t repFloats = repBytes / sizeof(float);
    float *W0Ta = nullptr, *W0Tb = nullptr, *W1Ta = nullptr, *W1Tb = nullptr;
    if (rep && (repBytes + trFloats * sizeof(float) <= ws_size)) {
        float* trbase = (float*)d_ws + repFloats;
        W0Ta = trbase;
        W0Tb = W0Ta + W0T_ALLOC;
        W1Ta = W0Tb + W0T_ALLOC;
        W1Tb = W1Ta + HID * HID;
    }

    if (rep) {
        hipMemsetAsync(d_ws, 0, repBytes, stream);
    } else {
        hipMemsetAsync(d_out, 0, (size_t)out_size * sizeof(float), stream);
    }

    if (W0Ta) {
        int nb = (DDIM * HID + 255) / 256;
        tr_kernel<<<dim3(nb), dim3(256), 0, stream>>>(
            (const float*)d_in[3], (const float*)d_in[9],
            (const float*)d_in[5], (const float*)d_in[11],
            W0Ta, W0Tb, W1Ta, W1Tb);
    }

    md_kernel<<<dim3(BN), dim3(BLOCK), 0, stream>>>(
        xyz, types, boxp,
        (const float*)d_in[3],  (const float*)d_in[4],
        (const float*)d_in[5],  (const float*)d_in[6],
        (const float*)d_in[7],  (const float*)d_in[8],
        (const float*)d_in[9],  (const float*)d_in[10],
        (const float*)d_in[11], (const float*)d_in[12],
        (const float*)d_in[13], (const float*)d_in[14],
        W0Ta, W0Tb, W1Ta, W1Tb,
        (float*)d_out, rep, nrep > 0 ? nrep : 1, eoff, rstride, B, N);

    if (rep) {
        int total = out_size;
        int nb = (total + 255) / 256;
        reduce_kernel<<<dim3(nb), dim3(256), 0, stream>>>(
            rep, (float*)d_out, total, B, eoff, rstride, nrep);
    }
}